// Round 7
// baseline (109.473 us; speedup 1.0000x reference)
//
#include <hip/hip_runtime.h>

typedef unsigned short u16;
typedef unsigned int u32;
typedef __attribute__((ext_vector_type(8))) short bf16x8;
typedef __attribute__((ext_vector_type(4))) float f32x4;

#define NUM_OPS 8
#define M_DIM 4096   // B*T
#define K_DIM 1024
#define N_DIM 1024
#define BK 32
#define KITERS (K_DIM / BK)   // 32 k-tiles
// Fragment-tiled operands: 1KB chunks = 16 rows x 32 k; slot l (16B) holds
// row (l&15), k=(l>>4)*8+j  == exact MFMA A/B fragment lane order.
// chunk index = rowtile*32 + ktile.

// ---- helpers ----------------------------------------------------------

__device__ __forceinline__ u16 f2b(float f) {
  union { float f; u32 u; } v; v.f = f;
  u32 r = v.u + 0x7fffu + ((v.u >> 16) & 1u);  // RNE
  return (u16)(r >> 16);
}

__device__ __forceinline__ u32 pk2(float a, float b) {  // bf16(a) | bf16(b)<<16
  return (u32)f2b(a) | ((u32)f2b(b) << 16);
}

__device__ __forceinline__ int compute_idx(const float* __restrict__ logits,
                                           const float* __restrict__ u) {
  int best = 0; float bv = -3.4e38f;
#pragma unroll
  for (int i = 0; i < NUM_OPS; ++i) {
    float v = logits[i] - logf(-logf(u[i]));  // logits + gumbel
    if (v > bv) { bv = v; best = i; }
  }
  return best;
}

// async global->LDS, 16B/lane
__device__ __forceinline__ void gld_lds16(const void* g, void* l) {
  __builtin_amdgcn_global_load_lds(
      (__attribute__((address_space(1))) void*)(g),
      (__attribute__((address_space(3))) void*)(unsigned)(unsigned long long)(l),
      16, 0, 0);
}

// ---- prep: x -> xb (frag-tiled bf16), W[idx] -> wt (frag-tiled bf16) ----
// (unchanged from R5/R6 — verified)
__global__ void prep_kernel(const float* __restrict__ x, const float* __restrict__ W,
                            const float* __restrict__ logits, const float* __restrict__ u,
                            u16* __restrict__ xb, u16* __restrict__ wt) {
  const int tid = threadIdx.x;
  const int bid = blockIdx.x;
  if (bid < 2048) {
    const int chunk = bid * 4 + (tid >> 6), l = tid & 63;
    const int mtile = chunk >> 5, ktile = chunk & 31;
    const float* src = x + (size_t)(mtile * 16 + (l & 15)) * K_DIM
                         + ktile * 32 + (l >> 4) * 8;
    float4 f0 = *(const float4*)(src);
    float4 f1 = *(const float4*)(src + 4);
    uint4 p;
    p.x = pk2(f0.x, f0.y); p.y = pk2(f0.z, f0.w);
    p.z = pk2(f1.x, f1.y); p.w = pk2(f1.z, f1.w);
    *(uint4*)(xb + (size_t)chunk * 512 + l * 8) = p;
  } else {
    __shared__ u16 t[64][66];  // [k][n], +2 pad
    const int wb = bid - 2048;
    const int kt = wb >> 4, nt = wb & 15;   // 64x64 tile of W[k][n]
    const int idx = compute_idx(logits, u);
    const float* Wi = W + (size_t)idx * K_DIM * N_DIM;
#pragma unroll
    for (int it = 0; it < 16; ++it) {
      int i = it * 256 + tid;
      int r = i >> 6, c = i & 63;
      t[r][c] = f2b(Wi[(size_t)(kt * 64 + r) * N_DIM + nt * 64 + c]);
    }
    __syncthreads();
#pragma unroll
    for (int it = 0; it < 2; ++it) {
      int s = it * 256 + tid;
      int c = s >> 6, l = s & 63;
      int ntl = c & 3, ktl = c >> 2;
      int kb = ktl * 32 + (l >> 4) * 8, nn = ntl * 16 + (l & 15);
      uint4 p;
      p.x = (u32)t[kb + 0][nn] | ((u32)t[kb + 1][nn] << 16);
      p.y = (u32)t[kb + 2][nn] | ((u32)t[kb + 3][nn] << 16);
      p.z = (u32)t[kb + 4][nn] | ((u32)t[kb + 5][nn] << 16);
      p.w = (u32)t[kb + 6][nn] | ((u32)t[kb + 7][nn] << 16);
      int chunk = (nt * 4 + ntl) * 32 + (kt * 2 + ktl);
      *(uint4*)(wt + (size_t)chunk * 512 + l * 8) = p;
    }
  }
}

// ---- GEMM: out = x * W[idx] + b[idx] -----------------------------------
// BM=128, BN=64, BK=32; 4 waves stacked in m (wave tile 32x64).
// A: DIRECT global->VGPR fragment loads (frag-tiled xb, coalesced dwordx4),
//    register double-buffered, never touches LDS, no barrier dependency.
// B: gld_lds16 -> 8KB dbuf LDS (4 chunks/iter, 1 per wave), 1 barrier/iter.
// Grid 512 = 2 blocks/CU (independent barrier groups).
__global__ __launch_bounds__(256) void gemm_kernel(
    const u16* __restrict__ xb, const u16* __restrict__ wt,
    const float* __restrict__ bvec, const float* __restrict__ logits,
    const float* __restrict__ u, float* __restrict__ out) {
  __shared__ u16 sB[2][4 * 512];  // [buf][4 chunks], 4KB each

  const int tid = threadIdx.x;
  const int w = tid >> 6, L = tid & 63;
  const int bid = blockIdx.x;
  // XCD swizzle: per XCD (bid&7): 4 m-slabs (1MB xb) + all nb (2MB wt) ~ L2
  const int mb = (bid & 7) * 4 + ((bid >> 3) & 3);  // [0,32)
  const int nb = bid >> 5;                          // [0,16)
  const int m0 = mb * 128, n0 = nb * 64;

  // A: wave w owns rows [32w, 32w+32) = mtiles {mb*8+2w, mb*8+2w+1}
  const u16* gA0 = xb + ((size_t)(mb * 8 + 2 * w) * 32) * 512 + L * 8;
  const u16* gA1 = gA0 + 32 * 512;  // next mtile
  // B: wave w stages chunk (nb*4 + w)
  const u16* gB = wt + ((size_t)(nb * 4 + w) * 32) * 512 + L * 8;
  const int lB = w * 512 + L * 8;

  f32x4 acc[2][4] = {};

  // prologue: k-tile 0
  gld_lds16(gB, &sB[0][lB]);
  bf16x8 ra[2][2];  // [buf][chunk]
  ra[0][0] = *(const bf16x8*)(gA0);
  ra[0][1] = *(const bf16x8*)(gA1);

  for (int kk = 0; kk < KITERS; ++kk) {
    const int cur = kk & 1, nxt = cur ^ 1;
    __syncthreads();  // drains vmcnt: B(kk) landed; prior reads of sB[nxt] done

    if (kk + 1 < KITERS) {
      const int ko = (kk + 1) * 512;
      gld_lds16(gB + ko, &sB[nxt][lB]);         // B(k+1), lands by next barrier
      ra[nxt][0] = *(const bf16x8*)(gA0 + ko);  // A(k+1), reg dbuf (vmcnt-gated)
      ra[nxt][1] = *(const bf16x8*)(gA1 + ko);
    }

    bf16x8 bf[4];
#pragma unroll
    for (int t = 0; t < 4; ++t) bf[t] = *(const bf16x8*)(&sB[cur][t * 512 + L * 8]);
#pragma unroll
    for (int f = 0; f < 2; ++f)
#pragma unroll
      for (int t = 0; t < 4; ++t)
        acc[f][t] = __builtin_amdgcn_mfma_f32_16x16x32_bf16(
            ra[cur][f], bf[t], acc[f][t], 0, 0, 0);
    // no trailing barrier: sB[nxt] writers gated by this iter's barrier
  }

  // epilogue: C/D layout col=lane&15, row=(lane>>4)*4+reg
  const int idx = compute_idx(logits, u);
  const float* bi = bvec + (size_t)idx * N_DIM;
#pragma unroll
  for (int f = 0; f < 2; ++f) {
    int row = m0 + 32 * w + 16 * f + (L >> 4) * 4;
#pragma unroll
    for (int t = 0; t < 4; ++t) {
      int col = n0 + 16 * t + (L & 15);
      float bv = bi[col];
#pragma unroll
      for (int r = 0; r < 4; ++r)
        out[(size_t)(row + r) * N_DIM + col] = acc[f][t][r] + bv;
    }
  }
}

// ---- launch -----------------------------------------------------------

extern "C" void kernel_launch(void* const* d_in, const int* in_sizes, int n_in,
                              void* d_out, int out_size, void* d_ws, size_t ws_size,
                              hipStream_t stream) {
  const float* x      = (const float*)d_in[0];
  const float* W      = (const float*)d_in[1];
  const float* bvec   = (const float*)d_in[2];
  const float* logits = (const float*)d_in[3];
  const float* u      = (const float*)d_in[4];
  float* out = (float*)d_out;

  u16* xb = (u16*)d_ws;                          // frag-tiled x, 8 MB
  u16* wt = (u16*)d_ws + (size_t)M_DIM * K_DIM;  // frag-tiled W[idx], 2 MB

  prep_kernel<<<2048 + 256, 256, 0, stream>>>(x, W, logits, u, xb, wt);
  gemm_kernel<<<512, 256, 0, stream>>>(xb, wt, bvec, logits, u, out);
}

// Round 8
// 106.531 us; speedup vs baseline: 1.0276x; 1.0276x over previous
//
#include <hip/hip_runtime.h>

typedef unsigned short u16;
typedef unsigned int u32;
typedef __attribute__((ext_vector_type(8))) short bf16x8;
typedef __attribute__((ext_vector_type(4))) float f32x4;

#define NUM_OPS 8
#define M_DIM 4096   // B*T
#define K_DIM 1024
#define N_DIM 1024
#define BK 64
#define KITERS (K_DIM / BK)   // 16
// Fragment-tiled operands: 1KB chunks = 16 rows x 32 k; slot l (16B) holds
// row (l&15), k=(l>>4)*8+j  == exact MFMA A/B fragment lane order.
// chunk index = rowtile*32 + ktile (ktile of 32).

// ---- helpers ----------------------------------------------------------

__device__ __forceinline__ u16 f2b(float f) {
  union { float f; u32 u; } v; v.f = f;
  u32 r = v.u + 0x7fffu + ((v.u >> 16) & 1u);  // RNE
  return (u16)(r >> 16);
}

__device__ __forceinline__ u32 pk2(float a, float b) {  // bf16(a) | bf16(b)<<16
  return (u32)f2b(a) | ((u32)f2b(b) << 16);
}

__device__ __forceinline__ int compute_idx(const float* __restrict__ logits,
                                           const float* __restrict__ u) {
  int best = 0; float bv = -3.4e38f;
#pragma unroll
  for (int i = 0; i < NUM_OPS; ++i) {
    float v = logits[i] - logf(-logf(u[i]));  // logits + gumbel
    if (v > bv) { bv = v; best = i; }
  }
  return best;
}

// async global->LDS, 16B/lane
__device__ __forceinline__ void gld_lds16(const void* g, void* l) {
  __builtin_amdgcn_global_load_lds(
      (__attribute__((address_space(1))) void*)(g),
      (__attribute__((address_space(3))) void*)(unsigned)(unsigned long long)(l),
      16, 0, 0);
}

// ---- prep: x -> xb (frag-tiled bf16), W[idx] -> wt (frag-tiled bf16) ----
// (unchanged since R5 — verified)
__global__ void prep_kernel(const float* __restrict__ x, const float* __restrict__ W,
                            const float* __restrict__ logits, const float* __restrict__ u,
                            u16* __restrict__ xb, u16* __restrict__ wt) {
  const int tid = threadIdx.x;
  const int bid = blockIdx.x;
  if (bid < 2048) {
    const int chunk = bid * 4 + (tid >> 6), l = tid & 63;
    const int mtile = chunk >> 5, ktile = chunk & 31;
    const float* src = x + (size_t)(mtile * 16 + (l & 15)) * K_DIM
                         + ktile * 32 + (l >> 4) * 8;
    float4 f0 = *(const float4*)(src);
    float4 f1 = *(const float4*)(src + 4);
    uint4 p;
    p.x = pk2(f0.x, f0.y); p.y = pk2(f0.z, f0.w);
    p.z = pk2(f1.x, f1.y); p.w = pk2(f1.z, f1.w);
    *(uint4*)(xb + (size_t)chunk * 512 + l * 8) = p;
  } else {
    __shared__ u16 t[64][66];  // [k][n], +2 pad
    const int wb = bid - 2048;
    const int kt = wb >> 4, nt = wb & 15;   // 64x64 tile of W[k][n]
    const int idx = compute_idx(logits, u);
    const float* Wi = W + (size_t)idx * K_DIM * N_DIM;
#pragma unroll
    for (int it = 0; it < 16; ++it) {
      int i = it * 256 + tid;
      int r = i >> 6, c = i & 63;
      t[r][c] = f2b(Wi[(size_t)(kt * 64 + r) * N_DIM + nt * 64 + c]);
    }
    __syncthreads();
#pragma unroll
    for (int it = 0; it < 2; ++it) {
      int s = it * 256 + tid;
      int c = s >> 6, l = s & 63;
      int ntl = c & 3, ktl = c >> 2;
      int kb = ktl * 32 + (l >> 4) * 8, nn = ntl * 16 + (l & 15);
      uint4 p;
      p.x = (u32)t[kb + 0][nn] | ((u32)t[kb + 1][nn] << 16);
      p.y = (u32)t[kb + 2][nn] | ((u32)t[kb + 3][nn] << 16);
      p.z = (u32)t[kb + 4][nn] | ((u32)t[kb + 5][nn] << 16);
      p.w = (u32)t[kb + 6][nn] | ((u32)t[kb + 7][nn] << 16);
      int chunk = (nt * 4 + ntl) * 32 + (kt * 2 + ktl);
      *(uint4*)(wt + (size_t)chunk * 512 + l * 8) = p;
    }
  }
}

// ---- GEMM: out = x * W[idx] + b[idx] -----------------------------------
// BM=64, BN=64, BK=64; 256 thr = 4 waves (2m x 2n), wave tile 32x32.
// Grid 1024 = 4 blocks/CU = 4 waves/SIMD: four INDEPENDENT barrier groups
// per CU — barrier drains and L2 latency overlap across blocks (m114).
// 16 chunks/iter staged via gld_lds16 (4/wave); dbuf; one barrier/iter.
__global__ __launch_bounds__(256) void gemm_kernel(
    const u16* __restrict__ xb, const u16* __restrict__ wt,
    const float* __restrict__ bvec, const float* __restrict__ logits,
    const float* __restrict__ u, float* __restrict__ out) {
  // unified chunk store: A items 0..7 (mt*2+dk), B items 8..15 (nt*2+dk)
  __shared__ u16 sm[2][16 * 512];  // 16KB per buf

  const int tid = threadIdx.x;
  const int w = tid >> 6, L = tid & 63;
  const int bid = blockIdx.x;
  // XCD swizzle: XCD x=bid&7 owns mb in [8x,8x+8) -> 1MB xb slab + 2MB wt in L2
  const int mb = ((bid & 7) << 3) | (bid >> 7);  // [0,64): 64-row m-slab
  const int nb = (bid >> 3) & 15;                // [0,16): 64-col n-slab

  // staging: wave w handles items 4w..4w+3
  const u16* gsrc[4];
  int lofs[4];
#pragma unroll
  for (int j = 0; j < 4; ++j) {
    int item = 4 * w + j;
    if (item < 8) {
      int mt = item >> 1, dk = item & 1;
      gsrc[j] = xb + ((size_t)((mb * 4 + mt) * 32 + dk)) * 512 + L * 8;
    } else {
      int t = item - 8, nt = t >> 1, dk = t & 1;
      gsrc[j] = wt + ((size_t)((nb * 4 + nt) * 32 + dk)) * 512 + L * 8;
    }
    lofs[j] = item * 512 + L * 8;
  }

  const int wm = w & 1, wn = w >> 1;
  // frag offsets: A local chunk = mt*2+dk (mt in {2wm,2wm+1}), B = 8+nt*2+dk
  int aoff[2][2], boff[2][2];
#pragma unroll
  for (int f = 0; f < 2; ++f)
#pragma unroll
    for (int dk = 0; dk < 2; ++dk) {
      aoff[f][dk] = ((2 * wm + f) * 2 + dk) * 512 + L * 8;
      boff[f][dk] = (8 + (2 * wn + f) * 2 + dk) * 512 + L * 8;
    }

  f32x4 acc[2][2] = {};

  // prologue: stage k-iter 0 into buf 0
#pragma unroll
  for (int j = 0; j < 4; ++j) gld_lds16(gsrc[j], &sm[0][lofs[j]]);

  for (int kk = 0; kk < KITERS; ++kk) {
    const int cur = kk & 1, nxt = cur ^ 1;
    __syncthreads();  // vmcnt drain: buf[cur] staged; prior reads of buf[nxt] done

    if (kk + 1 < KITERS) {
      const int ko = (kk + 1) * 1024;  // 2 ktiles (512 u16 each) per iter
#pragma unroll
      for (int j = 0; j < 4; ++j) gld_lds16(gsrc[j] + ko, &sm[nxt][lofs[j]]);
    }

    bf16x8 af[2][2], bf[2][2];
#pragma unroll
    for (int f = 0; f < 2; ++f)
#pragma unroll
      for (int dk = 0; dk < 2; ++dk) {
        af[f][dk] = *(const bf16x8*)(&sm[cur][aoff[f][dk]]);
        bf[f][dk] = *(const bf16x8*)(&sm[cur][boff[f][dk]]);
      }
#pragma unroll
    for (int dk = 0; dk < 2; ++dk)
#pragma unroll
      for (int f = 0; f < 2; ++f)
#pragma unroll
        for (int t = 0; t < 2; ++t)
          acc[f][t] = __builtin_amdgcn_mfma_f32_16x16x32_bf16(
              af[f][dk], bf[t][dk], acc[f][t], 0, 0, 0);
    // no trailing barrier: buf[nxt] writers gated by this iter's barrier
  }

  // epilogue: C/D layout col=lane&15, row=(lane>>4)*4+reg
  const int idx = compute_idx(logits, u);
  const float* bi = bvec + (size_t)idx * N_DIM;
#pragma unroll
  for (int f = 0; f < 2; ++f) {
    int row = mb * 64 + 32 * wm + 16 * f + (L >> 4) * 4;
#pragma unroll
    for (int t = 0; t < 2; ++t) {
      int col = nb * 64 + 32 * wn + 16 * t + (L & 15);
      float bv = bi[col];
#pragma unroll
      for (int r = 0; r < 4; ++r)
        out[(size_t)(row + r) * N_DIM + col] = acc[f][t][r] + bv;
    }
  }
}

// ---- launch -----------------------------------------------------------

extern "C" void kernel_launch(void* const* d_in, const int* in_sizes, int n_in,
                              void* d_out, int out_size, void* d_ws, size_t ws_size,
                              hipStream_t stream) {
  const float* x      = (const float*)d_in[0];
  const float* W      = (const float*)d_in[1];
  const float* bvec   = (const float*)d_in[2];
  const float* logits = (const float*)d_in[3];
  const float* u      = (const float*)d_in[4];
  float* out = (float*)d_out;

  u16* xb = (u16*)d_ws;                          // frag-tiled x, 8 MB
  u16* wt = (u16*)d_ws + (size_t)M_DIM * K_DIM;  // frag-tiled W[idx], 2 MB

  prep_kernel<<<2048 + 256, 256, 0, stream>>>(x, W, logits, u, xb, wt);
  gemm_kernel<<<1024, 256, 0, stream>>>(xb, wt, bvec, logits, u, out);
}